// Round 1
// baseline (89.394 us; speedup 1.0000x reference)
//
#include <hip/hip_runtime.h>
#include <hip/hip_bf16.h>

// Problem constants (fixed by the reference)
#define B_DIM   8
#define S_LEN   4096
#define H_DIM   1024
#define HID_DIM 128
#define NSPEC   5
#define NROWS   (HID_DIM + 1 + NSPEC)   // 129 interval rows + 5 special rows = 134
#define SLOPE   0.01f
#define LN_EPS  1e-12f

// ---------------------------------------------------------------------------
// Kernel 1: breakpoints t_k = -b1_k / W1_k, stable rank via O(n^2) count.
// One block, 128 threads.
// ---------------------------------------------------------------------------
__global__ void prep_kernel(const float* __restrict__ W1,
                            const float* __restrict__ b1,
                            float* __restrict__ sorted_t,
                            int* __restrict__ rank) {
    __shared__ float tsh[HID_DIM];
    const int k = threadIdx.x;            // 0..127
    const float w = W1[k];
    const float b = b1[k];
    const float t = (w != 0.0f) ? (-b / w) : __builtin_inff();
    tsh[k] = t;
    __syncthreads();
    int r = 0;
    for (int k2 = 0; k2 < HID_DIM; ++k2) {
        const float t2 = tsh[k2];
        if (t2 < t || (t2 == t && k2 < k)) ++r;   // stable tie-break
    }
    sorted_t[r] = t;
    rank[k]     = r;
}

// ---------------------------------------------------------------------------
// Kernel 2: build table rows.
//   rows 0..128 : interval i -> (u_i, v_i) with expr_e = x*u + v  (b2 folded in)
//   rows 129..133: special m -> (0, leaky(special_emb[m]) @ W2 + b2)
// grid (NROWS, 4), 256 threads; thread handles one output column j.
// ---------------------------------------------------------------------------
__global__ void build_kernel(const float* __restrict__ W1,
                             const float* __restrict__ b1,
                             const float* __restrict__ W2,
                             const float* __restrict__ b2,
                             const float* __restrict__ spec,
                             const int* __restrict__ rank,
                             float2* __restrict__ tab) {
    const int row = blockIdx.x;
    const int tid = threadIdx.x;
    const int j   = blockIdx.y * 256 + tid;

    __shared__ float ash[HID_DIM];
    __shared__ float csh[HID_DIM];
    if (tid < HID_DIM) {
        float a, c;
        if (row <= HID_DIM) {
            // interval row: s_k = 1 if z_k >= 0 in this interval else slope^2
            const float w = W1[tid];
            const float b = b1[tid];
            const bool crossed = (rank[tid] < row);      // t_k <= x for this interval
            bool zpos;
            if (w > 0.0f)      zpos = crossed;           // z>=0 <=> x >= t_k
            else if (w < 0.0f) zpos = !crossed;          // z>=0 <=> x <= t_k
            else               zpos = (b >= 0.0f);       // constant sign
            const float s = zpos ? 1.0f : (SLOPE * SLOPE);
            a = s * w;
            c = s * b;
        } else {
            // special row: u = 0, v = leaky(spec_e) @ W2 + b2
            const int m = row - (HID_DIM + 1);
            const float e = spec[m * HID_DIM + tid];
            a = 0.0f;
            c = (e >= 0.0f) ? e : SLOPE * e;
        }
        ash[tid] = a;
        csh[tid] = c;
    }
    __syncthreads();

    float u = 0.0f, v = 0.0f;
    #pragma unroll 4
    for (int k = 0; k < HID_DIM; ++k) {
        const float w2 = W2[k * H_DIM + j];   // coalesced across threads
        u = fmaf(ash[k], w2, u);
        v = fmaf(csh[k], w2, v);
    }
    tab[(size_t)row * H_DIM + j] = make_float2(u, v + b2[j]);
}

// ---------------------------------------------------------------------------
// Kernel 3: fused gather + table-lookup MLP + pos add + LayerNorm.
// One block (256 threads) per token; thread handles 4 consecutive H elems.
// ---------------------------------------------------------------------------
__global__ __launch_bounds__(256) void fuse_kernel(
        const int*   __restrict__ gene_ids,
        const float* __restrict__ expr,
        const float* __restrict__ gene_emb,
        const float* __restrict__ pos_emb,
        const float* __restrict__ gamma,
        const float* __restrict__ beta,
        const float* __restrict__ sorted_t,
        const float2* __restrict__ tab,
        float* __restrict__ out) {
    const int t   = blockIdx.x;          // token index, 0..B*S-1
    const int tid = threadIdx.x;         // 0..255
    const int s   = t & (S_LEN - 1);     // S = 4096 (pow2)

    __shared__ float  st[HID_DIM];
    __shared__ float2 wred[4];
    if (tid < HID_DIM) st[tid] = sorted_t[tid];
    __syncthreads();

    const float x = expr[t];
    int   row;
    float xm;
    if (x < 0.0f) {
        int m = -((int)x) - 1;                      // trunc-toward-zero == jnp astype
        m = min(max(m, 0), NSPEC - 1);
        row = HID_DIM + 1 + m;
        xm  = 0.0f;                                 // u-row is zero anyway
    } else {
        // row = #{ t_k <= x }  (upper-bound binary search, block-uniform)
        int lo = 0, hi = HID_DIM;
        while (lo < hi) {
            const int mid = (lo + hi) >> 1;
            if (st[mid] <= x) lo = mid + 1; else hi = mid;
        }
        row = lo;
        xm  = x;
    }

    const int gid = gene_ids[t];
    const float4 g = reinterpret_cast<const float4*>(gene_emb + (size_t)gid * H_DIM)[tid];
    const float4 p = reinterpret_cast<const float4*>(pos_emb  + (size_t)s   * H_DIM)[tid];
    const float4* tb = reinterpret_cast<const float4*>(tab + (size_t)row * H_DIM) + tid * 2;
    const float4 ta = tb[0];   // (u0, v0, u1, v1)
    const float4 tc = tb[1];   // (u2, v2, u3, v3)

    const float e0 = g.x + fmaf(xm, ta.x, ta.y) + p.x;
    const float e1 = g.y + fmaf(xm, ta.z, ta.w) + p.y;
    const float e2 = g.z + fmaf(xm, tc.x, tc.y) + p.z;
    const float e3 = g.w + fmaf(xm, tc.z, tc.w) + p.w;

    float s1 = e0 + e1 + e2 + e3;
    float s2 = e0*e0 + e1*e1 + e2*e2 + e3*e3;
    #pragma unroll
    for (int off = 32; off >= 1; off >>= 1) {
        s1 += __shfl_xor(s1, off, 64);
        s2 += __shfl_xor(s2, off, 64);
    }
    if ((tid & 63) == 0) wred[tid >> 6] = make_float2(s1, s2);
    __syncthreads();
    const float S1 = wred[0].x + wred[1].x + wred[2].x + wred[3].x;
    const float S2 = wred[0].y + wred[1].y + wred[2].y + wred[3].y;

    const float inv  = 1.0f / (float)H_DIM;
    const float mu   = S1 * inv;
    const float var  = S2 * inv - mu * mu;
    const float rsig = rsqrtf(var + LN_EPS);

    const float4 gm = reinterpret_cast<const float4*>(gamma)[tid];
    const float4 bt = reinterpret_cast<const float4*>(beta)[tid];
    float4 o;
    o.x = fmaf((e0 - mu) * rsig, gm.x, bt.x);
    o.y = fmaf((e1 - mu) * rsig, gm.y, bt.y);
    o.z = fmaf((e2 - mu) * rsig, gm.z, bt.z);
    o.w = fmaf((e3 - mu) * rsig, gm.w, bt.w);
    reinterpret_cast<float4*>(out + (size_t)t * H_DIM)[tid] = o;
}

// ---------------------------------------------------------------------------
extern "C" void kernel_launch(void* const* d_in, const int* in_sizes, int n_in,
                              void* d_out, int out_size, void* d_ws, size_t ws_size,
                              hipStream_t stream) {
    const int*   gene_ids = (const int*)  d_in[0];
    const float* expr     = (const float*)d_in[1];
    const float* gene_emb = (const float*)d_in[2];
    const float* W1       = (const float*)d_in[3];
    const float* b1       = (const float*)d_in[4];
    const float* W2       = (const float*)d_in[5];
    const float* b2       = (const float*)d_in[6];
    const float* spec     = (const float*)d_in[7];
    const float* pos_emb  = (const float*)d_in[8];
    const float* gamma    = (const float*)d_in[9];
    const float* beta     = (const float*)d_in[10];
    float* out = (float*)d_out;

    // workspace layout
    const size_t tab_bytes = (size_t)NROWS * H_DIM * sizeof(float2);  // ~1.07 MB
    float2* tab      = (float2*)d_ws;
    float*  sorted_t = (float*)((char*)d_ws + tab_bytes);
    int*    rank     = (int*)  ((char*)d_ws + tab_bytes + 512);

    const int n_tokens = in_sizes[0];   // B*S = 32768

    prep_kernel<<<1, HID_DIM, 0, stream>>>(W1, b1, sorted_t, rank);

    dim3 bgrid(NROWS, H_DIM / 256);     // 134 x 4
    build_kernel<<<bgrid, 256, 0, stream>>>(W1, b1, W2, b2, spec, rank, tab);

    fuse_kernel<<<n_tokens, 256, 0, stream>>>(gene_ids, expr, gene_emb, pos_emb,
                                              gamma, beta, sorted_t, tab, out);
}

// Round 2
// 80.599 us; speedup vs baseline: 1.1091x; 1.1091x over previous
//
#include <hip/hip_runtime.h>
#include <hip/hip_bf16.h>

// Problem constants (fixed by the reference)
#define B_DIM   8
#define S_LEN   4096
#define H_DIM   1024
#define HID_DIM 128
#define NSPEC   5
#define NROWS   (HID_DIM + 1 + NSPEC)   // 129 interval rows + 5 special rows = 134
#define SLOPE   0.01f
#define LN_EPS  1e-12f

// ---------------------------------------------------------------------------
// Kernel 1: build table rows (rank/breakpoint computation done in-block).
//   rows 0..128 : interval i -> (u_i, v_i) with expr_e(x) = x*u + v (b2 folded)
//   rows 129..133: special m -> (0, leaky(special_emb[m]) @ W2 + b2)
// grid (NROWS), 256 threads; thread handles 4 consecutive output columns.
// Block 0 additionally writes sorted breakpoints for the fuse kernel.
// ---------------------------------------------------------------------------
__global__ __launch_bounds__(256) void build_kernel(
        const float* __restrict__ W1,
        const float* __restrict__ b1,
        const float* __restrict__ W2,
        const float* __restrict__ b2,
        const float* __restrict__ spec,
        float* __restrict__ sorted_t,
        float2* __restrict__ tab) {
    const int row = blockIdx.x;
    const int tid = threadIdx.x;

    __shared__ float tsh[HID_DIM];
    __shared__ float ash[HID_DIM];
    __shared__ float csh[HID_DIM];

    float w = 0.0f, b = 0.0f, t = 0.0f;
    if (tid < HID_DIM) {
        w = W1[tid];
        b = b1[tid];
        t = (w != 0.0f) ? (-b / w) : __builtin_inff();
        tsh[tid] = t;
    }
    __syncthreads();
    if (tid < HID_DIM) {
        // stable rank of t among all breakpoints
        int r = 0;
        #pragma unroll 8
        for (int k2 = 0; k2 < HID_DIM; ++k2) {
            const float t2 = tsh[k2];
            if (t2 < t || (t2 == t && k2 < tid)) ++r;
        }
        if (row == 0) sorted_t[r] = t;   // one block publishes the sorted table

        float a, c;
        if (row <= HID_DIM) {
            const bool crossed = (r < row);              // t_k <= x in interval
            bool zpos;
            if (w > 0.0f)      zpos = crossed;
            else if (w < 0.0f) zpos = !crossed;
            else               zpos = (b >= 0.0f);
            const float s = zpos ? 1.0f : (SLOPE * SLOPE);
            a = s * w;
            c = s * b;
        } else {
            const int m = row - (HID_DIM + 1);
            const float e = spec[m * HID_DIM + tid];
            a = 0.0f;
            c = (e >= 0.0f) ? e : SLOPE * e;
        }
        ash[tid] = a;
        csh[tid] = c;
    }
    __syncthreads();

    // thread handles columns [4*tid .. 4*tid+3]
    float4 u = make_float4(0.f, 0.f, 0.f, 0.f);
    float4 v = make_float4(0.f, 0.f, 0.f, 0.f);
    #pragma unroll 4
    for (int k = 0; k < HID_DIM; ++k) {
        const float4 w2 = reinterpret_cast<const float4*>(W2 + (size_t)k * H_DIM)[tid];
        const float a = ash[k], c = csh[k];
        u.x = fmaf(a, w2.x, u.x);  v.x = fmaf(c, w2.x, v.x);
        u.y = fmaf(a, w2.y, u.y);  v.y = fmaf(c, w2.y, v.y);
        u.z = fmaf(a, w2.z, u.z);  v.z = fmaf(c, w2.z, v.z);
        u.w = fmaf(a, w2.w, u.w);  v.w = fmaf(c, w2.w, v.w);
    }
    const float4 bb = reinterpret_cast<const float4*>(b2)[tid];
    float4* trow = reinterpret_cast<float4*>(tab + (size_t)row * H_DIM);
    trow[2 * tid]     = make_float4(u.x, v.x + bb.x, u.y, v.y + bb.y);
    trow[2 * tid + 1] = make_float4(u.z, v.z + bb.z, u.w, v.w + bb.w);
}

// ---------------------------------------------------------------------------
// Kernel 2: fused gather + table-lookup MLP + pos add + LayerNorm.
// Wave-per-token: 256 threads = 4 waves = 4 tokens per block.
// ---------------------------------------------------------------------------
__global__ __launch_bounds__(256) void fuse_kernel(
        const int*   __restrict__ gene_ids,
        const float* __restrict__ expr,
        const float* __restrict__ gene_emb,
        const float* __restrict__ pos_emb,
        const float* __restrict__ gamma,
        const float* __restrict__ beta,
        const float* __restrict__ sorted_t,
        const float2* __restrict__ tab,
        float* __restrict__ out) {
    const int tid  = threadIdx.x;
    const int lane = tid & 63;
    const int t    = blockIdx.x * 4 + (tid >> 6);   // token index
    const int s    = t & (S_LEN - 1);               // S = 4096 (pow2)

    __shared__ float st[HID_DIM];
    if (tid < HID_DIM) st[tid] = sorted_t[tid];
    __syncthreads();

    const float x   = expr[t];
    const int   gid = gene_ids[t];

    const float4* gp = reinterpret_cast<const float4*>(gene_emb + (size_t)gid * H_DIM);
    const float4* pp = reinterpret_cast<const float4*>(pos_emb  + (size_t)s   * H_DIM);

    // issue gather + pos loads before the (LDS-dependent) interval search
    float4 g[4], p[4];
    #pragma unroll
    for (int q = 0; q < 4; ++q) {
        const int f = lane + 64 * q;
        g[q] = gp[f];
        p[q] = pp[f];
    }

    int   row;
    float xm;
    if (x < 0.0f) {
        int m = -((int)x) - 1;                      // trunc-toward-zero == astype
        m = min(max(m, 0), NSPEC - 1);
        row = HID_DIM + 1 + m;
        xm  = 0.0f;                                 // u-row is zero anyway
    } else {
        int lo = 0, hi = HID_DIM;                   // row = #{ t_k <= x }
        while (lo < hi) {
            const int mid = (lo + hi) >> 1;
            if (st[mid] <= x) lo = mid + 1; else hi = mid;
        }
        row = lo;
        xm  = x;
    }

    const float4* tp = reinterpret_cast<const float4*>(tab + (size_t)row * H_DIM);
    float4 e[4];
    float s1 = 0.0f, s2 = 0.0f;
    #pragma unroll
    for (int q = 0; q < 4; ++q) {
        const int f = lane + 64 * q;
        const float4 ta = tp[2 * f];       // (u0, v0, u1, v1)
        const float4 tb = tp[2 * f + 1];   // (u2, v2, u3, v3)
        float4 ev;
        ev.x = g[q].x + fmaf(xm, ta.x, ta.y) + p[q].x;
        ev.y = g[q].y + fmaf(xm, ta.z, ta.w) + p[q].y;
        ev.z = g[q].z + fmaf(xm, tb.x, tb.y) + p[q].z;
        ev.w = g[q].w + fmaf(xm, tb.z, tb.w) + p[q].w;
        e[q] = ev;
        s1 += ev.x + ev.y + ev.z + ev.w;
        s2 += ev.x * ev.x + ev.y * ev.y + ev.z * ev.z + ev.w * ev.w;
    }

    // 64-lane butterfly reduction (no LDS, no barrier)
    #pragma unroll
    for (int off = 32; off >= 1; off >>= 1) {
        s1 += __shfl_xor(s1, off, 64);
        s2 += __shfl_xor(s2, off, 64);
    }

    const float inv  = 1.0f / (float)H_DIM;
    const float mu   = s1 * inv;
    const float var  = s2 * inv - mu * mu;
    const float rsig = rsqrtf(var + LN_EPS);

    float4* op = reinterpret_cast<float4*>(out + (size_t)t * H_DIM);
    #pragma unroll
    for (int q = 0; q < 4; ++q) {
        const int f = lane + 64 * q;
        const float4 gm = reinterpret_cast<const float4*>(gamma)[f];
        const float4 bt = reinterpret_cast<const float4*>(beta)[f];
        float4 o;
        o.x = fmaf((e[q].x - mu) * rsig, gm.x, bt.x);
        o.y = fmaf((e[q].y - mu) * rsig, gm.y, bt.y);
        o.z = fmaf((e[q].z - mu) * rsig, gm.z, bt.z);
        o.w = fmaf((e[q].w - mu) * rsig, gm.w, bt.w);
        op[f] = o;
    }
}

// ---------------------------------------------------------------------------
extern "C" void kernel_launch(void* const* d_in, const int* in_sizes, int n_in,
                              void* d_out, int out_size, void* d_ws, size_t ws_size,
                              hipStream_t stream) {
    const int*   gene_ids = (const int*)  d_in[0];
    const float* expr     = (const float*)d_in[1];
    const float* gene_emb = (const float*)d_in[2];
    const float* W1       = (const float*)d_in[3];
    const float* b1       = (const float*)d_in[4];
    const float* W2       = (const float*)d_in[5];
    const float* b2       = (const float*)d_in[6];
    const float* spec     = (const float*)d_in[7];
    const float* pos_emb  = (const float*)d_in[8];
    const float* gamma    = (const float*)d_in[9];
    const float* beta     = (const float*)d_in[10];
    float* out = (float*)d_out;

    // workspace layout
    const size_t tab_bytes = (size_t)NROWS * H_DIM * sizeof(float2);  // ~1.07 MB
    float2* tab      = (float2*)d_ws;
    float*  sorted_t = (float*)((char*)d_ws + tab_bytes);

    const int n_tokens = in_sizes[0];   // B*S = 32768

    build_kernel<<<NROWS, 256, 0, stream>>>(W1, b1, W2, b2, spec, sorted_t, tab);
    fuse_kernel<<<n_tokens / 4, 256, 0, stream>>>(gene_ids, expr, gene_emb, pos_emb,
                                                  gamma, beta, sorted_t, tab, out);
}